// Round 4
// baseline (104.416 us; speedup 1.0000x reference)
//
#include <hip/hip_runtime.h>

typedef short short8 __attribute__((ext_vector_type(8)));
typedef float floatx4 __attribute__((ext_vector_type(4)));
typedef float floatx16 __attribute__((ext_vector_type(16)));
typedef unsigned int u32;

#define NEG_SLOPE 0.2f

// pack {bf16_rtne(b), bf16_rtne(a)} into one u32 (a in low half)
__device__ __forceinline__ u32 pk_rtne(float a, float b) {
    u32 ua = __float_as_uint(a); ua += 0x7fffu + ((ua >> 16) & 1u);
    u32 ub = __float_as_uint(b); ub += 0x7fffu + ((ub >> 16) & 1u);
    return __builtin_amdgcn_perm(ub, ua, 0x07060302);
}
// pack {trunc16(b), trunc16(a)} — 1 inst per pair
__device__ __forceinline__ u32 pk_trunc(float a, float b) {
    return __builtin_amdgcn_perm(__float_as_uint(b), __float_as_uint(a), 0x07060302);
}
__device__ __forceinline__ void gl_lds16(const void* g, void* l) {
    __builtin_amdgcn_global_load_lds((__attribute__((address_space(1))) u32*)(void*)g,
                                     (__attribute__((address_space(3))) u32*)l, 16, 0, 0);
}

// ---------------------------------------------------------------------------
// Kernel 1: Wh = h @ W^T (single-pass bf16 MFMA, 16x16x32), barrier-free main
// loop. Scores s1/s2 computed EXACTLY in fp32 via s = h · (W^T a)  (v-GEMV
// folded into the W staging pass). Outputs:
//  - WhF: Wh^T as pre-swizzled 32x32x16 MFMA *B*-fragments
//    [b4h][jt16(64)][nt32(2)][lane(64)][8 bf16]
//    with k-slot permutation pi(g,jj) = (jj&3) + 4*g + 8*(jj>>2)
//  - G1[b4h,i] = exp(-0.8*s1)   (E1 cancels in the softmax ratio)
//  - E2F2[b4h,j] = m_j*(exp(s2), exp(0.2*s2))
// ---------------------------------------------------------------------------
__global__ __launch_bounds__(256, 4) void k_wh(
    const float* __restrict__ hin, const int* __restrict__ mask,
    const float* __restrict__ W, const float* __restrict__ a,
    unsigned short* __restrict__ WhF, float* __restrict__ G1,
    float2* __restrict__ E2F2)
{
    __shared__ unsigned short sBF[8 * 4 * 64 * 8];  // W as 16x16x32 B-frags, 32 KB
    __shared__ float sV1[256], sV2[256];

    const int t = threadIdx.x;
    const int bi = blockIdx.x;
    const int mtile = bi & 255, hh = bi >> 8;
    const int m0g = mtile * 64;             // global row = b*1024 + i0
    const int b = m0g >> 10, i0 = m0g & 1023;
    const int b4h = b * 4 + hh;
    const int wid = t >> 6, lane = t & 63;
    const int l15 = lane & 15, q = lane >> 4;

    sV1[t] = 0.f;
    sV2[t] = 0.f;
    __syncthreads();

    // ---- stage W (this head) as B-frags + v1/v2 partial GEMV ----
    float vp1[8] = {0, 0, 0, 0, 0, 0, 0, 0};
    float vp2[8] = {0, 0, 0, 0, 0, 0, 0, 0};
    {
        const int c = t & 31;               // k-chunk of 8 floats
        const int rb = t >> 5;
#pragma unroll
        for (int i = 0; i < 8; ++i) {
            int row = i * 8 + rb;           // d within head
            const float* gp = &W[((size_t)(hh * 64 + row)) * 256 + c * 8];
            float4 w0 = *(const float4*)gp;
            float4 w1 = *(const float4*)(gp + 4);
            float a1r = a[row], a2r = a[64 + row];
            vp1[0] += a1r * w0.x; vp1[1] += a1r * w0.y; vp1[2] += a1r * w0.z; vp1[3] += a1r * w0.w;
            vp1[4] += a1r * w1.x; vp1[5] += a1r * w1.y; vp1[6] += a1r * w1.z; vp1[7] += a1r * w1.w;
            vp2[0] += a2r * w0.x; vp2[1] += a2r * w0.y; vp2[2] += a2r * w0.z; vp2[3] += a2r * w0.w;
            vp2[4] += a2r * w1.x; vp2[5] += a2r * w1.y; vp2[6] += a2r * w1.z; vp2[7] += a2r * w1.w;
            uint4 pv;
            pv.x = pk_rtne(w0.x, w0.y); pv.y = pk_rtne(w0.z, w0.w);
            pv.z = pk_rtne(w1.x, w1.y); pv.w = pk_rtne(w1.z, w1.w);
            int kt = c >> 2, qq = c & 3, nt = row >> 4, r15 = row & 15;
            int idx16 = (kt * 4 + nt) * 64 + qq * 16 + r15;
            *(uint4*)&sBF[(idx16 ^ kt) * 8] = pv;   // XOR swizzle: 32-way -> 4-way
        }
    }
#pragma unroll
    for (int j = 0; j < 8; ++j) {
        vp1[j] += __shfl_xor(vp1[j], 32, 64);
        vp2[j] += __shfl_xor(vp2[j], 32, 64);
    }
    if (lane < 32) {
        const int c = t & 31;
#pragma unroll
        for (int j = 0; j < 8; ++j) {
            atomicAdd(&sV1[c * 8 + j], vp1[j]);
            atomicAdd(&sV2[c * 8 + j], vp2[j]);
        }
    }
    __syncthreads();

    // ---- main loop: A-frags direct from global, no barriers ----
    floatx4 acc[4];
#pragma unroll
    for (int nt = 0; nt < 4; ++nt) {
        floatx4 z = {0.f, 0.f, 0.f, 0.f};
        acc[nt] = z;
    }
    float s1a = 0.f, s2a = 0.f;
    const float* hrow = &hin[((size_t)(m0g + wid * 16 + l15)) * 256 + q * 8];
#pragma unroll
    for (int kt = 0; kt < 8; ++kt) {
        float4 h0 = *(const float4*)(hrow + kt * 32);
        float4 h1 = *(const float4*)(hrow + kt * 32 + 4);
        float4 v1a = *(const float4*)&sV1[kt * 32 + q * 8];
        float4 v1b = *(const float4*)&sV1[kt * 32 + q * 8 + 4];
        float4 v2a = *(const float4*)&sV2[kt * 32 + q * 8];
        float4 v2b = *(const float4*)&sV2[kt * 32 + q * 8 + 4];
        s1a += h0.x * v1a.x + h0.y * v1a.y + h0.z * v1a.z + h0.w * v1a.w
             + h1.x * v1b.x + h1.y * v1b.y + h1.z * v1b.z + h1.w * v1b.w;
        s2a += h0.x * v2a.x + h0.y * v2a.y + h0.z * v2a.z + h0.w * v2a.w
             + h1.x * v2b.x + h1.y * v2b.y + h1.z * v2b.z + h1.w * v2b.w;
        union { short8 s; uint4 u; } af;
        af.u.x = pk_rtne(h0.x, h0.y); af.u.y = pk_rtne(h0.z, h0.w);
        af.u.z = pk_rtne(h1.x, h1.y); af.u.w = pk_rtne(h1.z, h1.w);
#pragma unroll
        for (int nt = 0; nt < 4; ++nt) {
            int idx16 = (kt * 4 + nt) * 64 + lane;
            short8 bf = *(const short8*)&sBF[(idx16 ^ kt) * 8];
            acc[nt] = __builtin_amdgcn_mfma_f32_16x16x32_bf16(af.s, bf, acc[nt], 0, 0, 0);
        }
    }

    // ---- epilogue: store WhF as 32x32x16 B-frags under pi ----
    const int jt16 = (i0 >> 4) + wid;
    const int g = q & 1, jb = (q >> 1) * 4;
#pragma unroll
    for (int nt = 0; nt < 4; ++nt) {
        int nt32 = nt >> 1;
        int l31 = (nt & 1) * 16 + l15;
        uint2 pv;
        pv.x = pk_rtne(acc[nt][0], acc[nt][1]);
        pv.y = pk_rtne(acc[nt][2], acc[nt][3]);
        size_t idx = ((((size_t)b4h * 64 + jt16) * 2 + nt32) * 64 + (g * 32 + l31)) * 8 + jb;
        *(uint2*)&WhF[idx] = pv;
    }

    // ---- scores: fold q (xor 16,32), write G1 / E2F2 ----
    s1a += __shfl_xor(s1a, 16, 64); s1a += __shfl_xor(s1a, 32, 64);
    s2a += __shfl_xor(s2a, 16, 64); s2a += __shfl_xor(s2a, 32, 64);
    if (lane < 16) {
        int i = i0 + wid * 16 + lane;
        G1[(size_t)b4h * 1024 + i] = __expf(-0.8f * s1a);
        int mj = mask[b * 1024 + i];
        E2F2[(size_t)b4h * 1024 + i] =
            make_float2(mj ? __expf(s2a) : 0.f, mj ? __expf(NEG_SLOPE * s2a) : 0.f);
    }
}

// ---------------------------------------------------------------------------
// Kernel 2: out[i,:] = (sum_j w'_ij Wh[j,:]) / (sum_j w'_ij),
// w'_ij = max(E2_j, G1_i*F2_j)   (row factor E1 cancels in the ratio).
// 32x32x16 MFMA; wave = 64 rows (2 A-frags) x HALF the j-range (wave pairs
// split j, partial-acc combine via reused sB) -> each ds_read_b128 B-frag
// feeds 2 MFMAs. Denominator via ones-column MFMA. 512 blocks = (b4h, 128 i).
// ---------------------------------------------------------------------------
__global__ __launch_bounds__(256, 2) void k_attn(
    const int* __restrict__ mask,
    const unsigned short* __restrict__ WhF,
    const float* __restrict__ G1, const float2* __restrict__ E2F2,
    float* __restrict__ out)
{
    __shared__ unsigned short sB[2][8192];   // [jtile(8)][nt(2)][lane][8], 16 KB/buf
    __shared__ float2 sEF[2][128];

    const int t = threadIdx.x;
    const int bi = blockIdx.x;
    const int b4h = bi & 63, ib = bi >> 6;
    const int b = b4h >> 2, hh = b4h & 3;
    const int i0 = ib * 128;
    const int wid = t >> 6, lane = t & 63;
    const int l31 = lane & 31, g = lane >> 5;
    const int pair = wid >> 1, half = wid & 1;
    const int iw = i0 + pair * 64;           // wave pair covers rows iw..iw+63

    const float g1a = G1[(size_t)b4h * 1024 + iw + l31];        // row-group 0: m=l31
    const float g1b = G1[(size_t)b4h * 1024 + iw + 32 + l31];   // row-group 1

    floatx16 acc00, acc01, acc10, acc11, accL0, accL1;
#pragma unroll
    for (int r = 0; r < 16; ++r) {
        acc00[r] = 0.f; acc01[r] = 0.f; acc10[r] = 0.f;
        acc11[r] = 0.f; accL0[r] = 0.f; accL1[r] = 0.f;
    }
    const short ob = (short)0x3F80;          // bf16 1.0
    const short8 ones = {ob, ob, ob, ob, ob, ob, ob, ob};

    const char* gbase = (const char*)WhF + (size_t)b4h * 131072;

    // prefetch jt=0
    {
#pragma unroll
        for (int i = 0; i < 4; ++i)
            gl_lds16(gbase + wid * 4096 + i * 1024 + lane * 16,
                     (char*)&sB[0][0] + wid * 4096 + i * 1024);
        if (wid == 1)
            gl_lds16((const char*)&E2F2[(size_t)b4h * 1024] + lane * 16, (char*)&sEF[0][0]);
    }

    for (int jt = 0; jt < 8; ++jt) {
        const int buf = jt & 1;
        __syncthreads();
        if (jt < 7) {
            const char* gp = gbase + (size_t)(jt + 1) * 16384;
#pragma unroll
            for (int i = 0; i < 4; ++i)
                gl_lds16(gp + wid * 4096 + i * 1024 + lane * 16,
                         (char*)&sB[buf ^ 1][0] + wid * 4096 + i * 1024);
            if (wid == 1)
                gl_lds16((const char*)&E2F2[(size_t)b4h * 1024 + (jt + 1) * 128] + lane * 16,
                         (char*)&sEF[buf ^ 1][0]);
        }
#pragma unroll
        for (int tl4 = 0; tl4 < 4; ++tl4) {
            const int tl = half * 4 + tl4;   // this wave's j-half of the buffer
            const int jb = tl * 16;
            // slots jj 0..7 <-> j = jb + {4g+0..3, 8+4g+0..3}   (pi map)
            const float4 eA0 = *(const float4*)&sEF[buf][jb + g * 4];
            const float4 eA1 = *(const float4*)&sEF[buf][jb + g * 4 + 2];
            const float4 eB0 = *(const float4*)&sEF[buf][jb + 8 + g * 4];
            const float4 eB1 = *(const float4*)&sEF[buf][jb + 8 + g * 4 + 2];
            union { short8 s; u32 u[4]; } af0, af1;
            af0.u[0] = pk_trunc(fmaxf(eA0.x, g1a * eA0.y), fmaxf(eA0.z, g1a * eA0.w));
            af0.u[1] = pk_trunc(fmaxf(eA1.x, g1a * eA1.y), fmaxf(eA1.z, g1a * eA1.w));
            af0.u[2] = pk_trunc(fmaxf(eB0.x, g1a * eB0.y), fmaxf(eB0.z, g1a * eB0.w));
            af0.u[3] = pk_trunc(fmaxf(eB1.x, g1a * eB1.y), fmaxf(eB1.z, g1a * eB1.w));
            af1.u[0] = pk_trunc(fmaxf(eA0.x, g1b * eA0.y), fmaxf(eA0.z, g1b * eA0.w));
            af1.u[1] = pk_trunc(fmaxf(eA1.x, g1b * eA1.y), fmaxf(eA1.z, g1b * eA1.w));
            af1.u[2] = pk_trunc(fmaxf(eB0.x, g1b * eB0.y), fmaxf(eB0.z, g1b * eB0.w));
            af1.u[3] = pk_trunc(fmaxf(eB1.x, g1b * eB1.y), fmaxf(eB1.z, g1b * eB1.w));
            short8 bf0 = *(const short8*)&sB[buf][((tl * 2 + 0) * 64 + lane) * 8];
            short8 bf1 = *(const short8*)&sB[buf][((tl * 2 + 1) * 64 + lane) * 8];
            acc00 = __builtin_amdgcn_mfma_f32_32x32x16_bf16(af0.s, bf0, acc00, 0, 0, 0);
            acc01 = __builtin_amdgcn_mfma_f32_32x32x16_bf16(af0.s, bf1, acc01, 0, 0, 0);
            acc10 = __builtin_amdgcn_mfma_f32_32x32x16_bf16(af1.s, bf0, acc10, 0, 0, 0);
            acc11 = __builtin_amdgcn_mfma_f32_32x32x16_bf16(af1.s, bf1, acc11, 0, 0, 0);
            accL0 = __builtin_amdgcn_mfma_f32_32x32x16_bf16(af0.s, ones, accL0, 0, 0, 0);
            accL1 = __builtin_amdgcn_mfma_f32_32x32x16_bf16(af1.s, ones, accL1, 0, 0, 0);
        }
    }

    // ---- combine j-halves across wave pairs (reuse sB as scratch) ----
    __syncthreads();                          // everyone done reading sB
    {
        float* sScr = (float*)&sB[0][0];      // 24 KB used: [pair][48][64 lanes]
        const int base = pair * 3072 + lane;
        if (half == 1) {
#pragma unroll
            for (int r = 0; r < 16; ++r) {
                sScr[base + r * 64]        = acc00[r];
                sScr[base + (r + 16) * 64] = acc01[r];
                sScr[base + (r + 32) * 64] = accL0[r];
            }
        }
        __syncthreads();
        if (half == 0) {
#pragma unroll
            for (int r = 0; r < 16; ++r) {
                acc00[r] += sScr[base + r * 64];
                acc01[r] += sScr[base + (r + 16) * 64];
                accL0[r] += sScr[base + (r + 32) * 64];
            }
            // hand group-1 partials to the half==1 wave (in-wave program order
            // guarantees our reads above complete before these writes)
#pragma unroll
            for (int r = 0; r < 16; ++r) {
                sScr[base + r * 64]        = acc10[r];
                sScr[base + (r + 16) * 64] = acc11[r];
                sScr[base + (r + 32) * 64] = accL1[r];
            }
        }
        __syncthreads();
        if (half == 1) {
#pragma unroll
            for (int r = 0; r < 16; ++r) {
                acc10[r] += sScr[base + r * 64];
                acc11[r] += sScr[base + (r + 16) * 64];
                accL1[r] += sScr[base + (r + 32) * 64];
            }
        }
    }

    // ---- epilogue: wave(pair,half) stores row-group `half` (32 rows) ----
    // C/D 32x32 layout: col = l31, row = (r&3) + 8*(r>>2) + 4*g
#pragma unroll
    for (int r = 0; r < 16; ++r) {
        int row = (r & 3) + 8 * (r >> 2) + 4 * g;
        int i = iw + half * 32 + row;
        float aA = half ? acc10[r] : acc00[r];
        float aB = half ? acc11[r] : acc01[r];
        float l  = half ? accL1[r] : accL0[r];
        int mi = mask[b * 1024 + i];
        float inv = (mi && l > 0.f) ? 1.0f / l : 0.f;
        size_t o = ((size_t)(b * 1024 + i)) * 256 + hh * 64;
        out[o + l31] = aA * inv;
        out[o + 32 + l31] = aB * inv;
    }
}

extern "C" void kernel_launch(void* const* d_in, const int* in_sizes, int n_in,
                              void* d_out, int out_size, void* d_ws, size_t ws_size,
                              hipStream_t stream) {
    const float* h = (const float*)d_in[0];
    const int* mask = (const int*)d_in[1];
    const float* W = (const float*)d_in[2];
    const float* a = (const float*)d_in[3];
    float* out = (float*)d_out;

    // ws: WhF bf16 frags [64 b4h][64 jt16][2 nt][64 lane][8] = 8 MiB;
    // then G1 (float [64][1024], 256 KB), E2F2 (float2 [64][1024], 512 KB)
    unsigned short* WhF = (unsigned short*)d_ws;
    float* G1 = (float*)((char*)d_ws + (size_t)64 * 64 * 2 * 64 * 8 * 2);
    float2* E2F2 = (float2*)(G1 + 64 * 1024);

    hipLaunchKernelGGL(k_wh, dim3(1024), dim3(256), 0, stream, h, mask, W, a, WhF, G1, E2F2);
    hipLaunchKernelGGL(k_attn, dim3(512), dim3(256), 0, stream, mask, WhF, G1, E2F2, out);
}